// Round 7
// baseline (216.267 us; speedup 1.0000x reference)
//
#include <hip/hip_runtime.h>
#include <hip/hip_bf16.h>
#include <stdint.h>
#include <stddef.h>

typedef __bf16 bf16_t;
typedef __bf16 bf16x4 __attribute__((ext_vector_type(4)));
typedef __bf16 bf16x8 __attribute__((ext_vector_type(8)));
typedef float f32x4 __attribute__((ext_vector_type(4)));

#define MFMA16(a, b, c) __builtin_amdgcn_mfma_f32_16x16x32_bf16(a, b, c, 0, 0, 0)

// async global->LDS, 16 B per lane; LDS dest = uniform base + lane*16
#define GLL16(g, l)                                                      \
    __builtin_amdgcn_global_load_lds(                                    \
        (const __attribute__((address_space(1))) void*)(g),              \
        (__attribute__((address_space(3))) void*)(l), 16, 0, 0)

#define SEQ 2048
#define NHEAD 16
#define HD 64
#define HID 1024
#define QKV_LD 3072
#define VT_LD 2080  // 2048 + 32 pad: breaks 4 KB power-of-2 L2 set aliasing

// ---------------------------------------------------------------------------
// Fused prep: cast x -> bf16 (blocks 0..4095), transpose+cast w_qkv
// (blocks 4096..7167), transpose+cast w_out (blocks 7168..8191).
// One launch instead of three (dispatch-gap cut).
// ---------------------------------------------------------------------------
__global__ __launch_bounds__(256)
void prep_kernel(const float* __restrict__ x, const float* __restrict__ w_qkv,
                 const float* __restrict__ w_out, bf16_t* __restrict__ xbf,
                 bf16_t* __restrict__ wqkvT, bf16_t* __restrict__ woutT) {
    int L = blockIdx.x;
    int tid = threadIdx.x;
    if (L < 4096) {  // cast x
        int i = (L * 256 + tid) * 4;
        float4 v = *(const float4*)(x + i);
        bf16x4 o = {(bf16_t)v.x, (bf16_t)v.y, (bf16_t)v.z, (bf16_t)v.w};
        *(bf16x4*)(xbf + i) = o;
        return;
    }
    __shared__ bf16_t tile[32][33];
    const float* W;
    bf16_t* Wt;
    int N, bx, by;
    if (L < 7168) {
        int r = L - 4096;
        W = w_qkv; Wt = wqkvT; N = 3072; bx = r % 96; by = r / 96;
    } else {
        int r = L - 7168;
        W = w_out; Wt = woutT; N = 1024; bx = r % 32; by = r / 32;
    }
    int K = 1024;
    int n0 = bx * 32, k0 = by * 32;
    int tx = tid & 31, ty = tid >> 5;  // 32 x 8
#pragma unroll
    for (int i = 0; i < 4; i++)
        tile[ty + i * 8][tx] = (bf16_t)W[(size_t)(k0 + ty + i * 8) * N + n0 + tx];
    __syncthreads();
#pragma unroll
    for (int i = 0; i < 4; i++)
        Wt[(size_t)(n0 + ty + i * 8) * K + k0 + tx] = tile[tx][ty + i * 8];
}

// ---------------------------------------------------------------------------
// V transpose prepass: Vt[bh][d][s] = qkv[b][s][2048 + h*64 + d].
// ---------------------------------------------------------------------------
__global__ __launch_bounds__(256)
void vt_transpose(const bf16_t* __restrict__ qkv, bf16_t* __restrict__ Vt) {
    int s0 = blockIdx.x * 64;
    int bh = blockIdx.y;
    int b = bh >> 4, h = bh & 15;
    int tid = threadIdx.x;
    __shared__ __align__(16) bf16_t tile[64][72];

    int row = tid >> 3, c8 = (tid & 7) * 8;
#pragma unroll
    for (int it = 0; it < 2; it++) {
        int sr = row + it * 32;
        bf16x8 v = *(const bf16x8*)(qkv + ((size_t)b * SEQ + s0 + sr) * QKV_LD +
                                    2 * HID + h * HD + c8);
        *(bf16x8*)(&tile[sr][c8]) = v;
    }
    __syncthreads();
#pragma unroll
    for (int it = 0; it < 2; it++) {
        int d = row + it * 32;
        bf16x8 w;
#pragma unroll
        for (int e = 0; e < 8; e++) w[e] = tile[c8 + e][d];
        *(bf16x8*)(Vt + ((size_t)bh * HD + d) * VT_LD + s0 + c8) = w;
    }
}

// ---------------------------------------------------------------------------
// GEMM: C[M][N] = A[M][K] @ Bt[N][K]^T + bias[N].  bf16, fp32 accum, OutT out.
// 128xTN tile (TN=128 or 64), BK=32, 256 thr, GLL width-16 staging into
// unpadded LDS (2-way read aliasing is free).
// ---------------------------------------------------------------------------
template <typename OutT, int TN>
__global__ __launch_bounds__(256)
void gemm_bt_bias(const bf16_t* __restrict__ A, const bf16_t* __restrict__ Bt,
                  const float* __restrict__ bias, OutT* __restrict__ C,
                  int M, int N, int K) {
    constexpr int NT = TN / 32;  // acc n-tiles per wave
    __shared__ __align__(16) bf16_t As[128][32];
    __shared__ __align__(16) bf16_t Bs[TN][32];

    int m0 = blockIdx.y * 128;
    int n0 = blockIdx.x * TN;
    int tid = threadIdx.x;
    int wave = tid >> 6, lane = tid & 63;
    int quad = lane >> 4, l16 = lane & 15;
    int wm = (wave >> 1) * 64, wn = (wave & 1) * (TN / 2);

    f32x4 acc[4][NT] = {};

    const bf16_t* a_base =
        A + (size_t)(m0 + wave * 32 + (lane >> 2)) * K + (lane & 3) * 8;
    const bf16_t* b_base =
        Bt + (size_t)(n0 + wave * (TN / 4) + (lane >> 2)) * K + (lane & 3) * 8;
    bf16_t* as_base = &As[wave * 32][0];
    bf16_t* bs_base = &Bs[wave * (TN / 4)][0];

    for (int k0 = 0; k0 < K; k0 += 32) {
        GLL16(a_base + k0, as_base);
        GLL16(a_base + 16 * K + k0, as_base + 16 * 32);
        GLL16(b_base + k0, bs_base);
        if (TN == 128) GLL16(b_base + 16 * K + k0, bs_base + 16 * 32);
        __syncthreads();

        bf16x8 af[4], bfr[NT];
#pragma unroll
        for (int t = 0; t < 4; t++)
            af[t] = *(const bf16x8*)(&As[wm + t * 16 + l16][quad * 8]);
#pragma unroll
        for (int t = 0; t < NT; t++)
            bfr[t] = *(const bf16x8*)(&Bs[wn + t * 16 + l16][quad * 8]);
#pragma unroll
        for (int mt = 0; mt < 4; mt++)
#pragma unroll
            for (int nt = 0; nt < NT; nt++)
                acc[mt][nt] = MFMA16(af[mt], bfr[nt], acc[mt][nt]);
        __syncthreads();
    }

#pragma unroll
    for (int mt = 0; mt < 4; mt++) {
        int row = m0 + wm + mt * 16 + quad * 4;
#pragma unroll
        for (int nt = 0; nt < NT; nt++) {
            int col = n0 + wn + nt * 16 + l16;
            float bv = bias[col];
#pragma unroll
            for (int r = 0; r < 4; r++)
                C[(size_t)(row + r) * N + col] = (OutT)(acc[mt][nt][r] + bv);
        }
    }
}

// ---------------------------------------------------------------------------
// Attention, mask j >= i.  One 64-row i-tile per block; grid 32x32 -> 4
// blocks/CU (LDS 35.8 KB: Ps aliases the Ks region, made safe by a 3rd
// barrier after QK^T).  Q pre-scaled by log2(e)/8 -> exp2 only in the hot
// path; mask hoisted to the first j-iteration (the only one containing the
// diagonal).  Row sums via ones-MFMA.  XCD swizzle: 4 bh per XCD.
// ---------------------------------------------------------------------------
__global__ __launch_bounds__(256, 4)
void attn_kernel(const bf16_t* __restrict__ qkv, const bf16_t* __restrict__ Vt,
                 bf16_t* __restrict__ attn_out) {
    int L = blockIdx.y * 32 + blockIdx.x;
    int xcd = L & 7, s5 = L >> 3;          // s5: 0..127
    int bh = xcd + 8 * (s5 >> 5);          // 4 bh groups per xcd
    int tile = s5 & 31;
    int b = bh >> 4, h = bh & 15;

    int tid = threadIdx.x, wave = tid >> 6, lane = tid & 63;
    int quad = lane >> 4, l16 = lane & 15;

    const bf16_t* q_g = qkv + (size_t)b * SEQ * QKV_LD + (size_t)h * HD;
    const bf16_t* k_g = q_g + HID;
    const bf16_t* vt_g = Vt + (size_t)bh * HD * VT_LD;

    __shared__ __align__(16) bf16_t Ks[128][72];   // K tile [j][d]; also Ps
    __shared__ __align__(16) bf16_t Vs[64][136];   // V^T tile [d][j]
    bf16_t* Ps_w = &Ks[wave * 32][0];              // wave-private [16][136]

    bf16x8 ones;
#pragma unroll
    for (int e = 0; e < 8; e++) ones[e] = (bf16_t)1.0f;

    int i0 = tile * 64;
    int iw = i0 + wave * 16;

    // Q fragments, pre-scaled by log2(e)/8 so P = exp2(s) directly.
    const float QS = 0.125f * 1.44269504088896f;
    bf16x8 qa0, qa1;
    {
        bf16x8 t0 = *(const bf16x8*)(q_g + (size_t)(iw + l16) * QKV_LD + quad * 8);
        bf16x8 t1 = *(const bf16x8*)(q_g + (size_t)(iw + l16) * QKV_LD + 32 + quad * 8);
#pragma unroll
        for (int e = 0; e < 8; e++) {
            qa0[e] = (bf16_t)((float)t0[e] * QS);
            qa1[e] = (bf16_t)((float)t1[e] * QS);
        }
    }

    f32x4 o[4] = {};
    f32x4 lacc = {};

    int krow = tid >> 3, kc8 = (tid & 7) * 8;    // K staging: 32 rows/pass
    int vrow = tid >> 4, vc8 = (tid & 15) * 8;   // V staging: 16 rows/pass

    int jstart = i0 & ~127;
    for (int j0 = jstart; j0 < SEQ; j0 += 128) {
        __syncthreads();  // prev iteration's Ks/Ps/Vs readers done
        // --- stage K[j0..j0+127][0..63], V^T[0..63][j0..j0+127] ---
#pragma unroll
        for (int t = 0; t < 4; t++) {
            bf16x8 kv = *(const bf16x8*)(k_g + (size_t)(j0 + krow + t * 32) * QKV_LD + kc8);
            *(bf16x8*)(&Ks[krow + t * 32][kc8]) = kv;
        }
#pragma unroll
        for (int t = 0; t < 4; t++) {
            bf16x8 vv = *(const bf16x8*)(vt_g + (size_t)(vrow + t * 16) * VT_LD + j0 + vc8);
            *(bf16x8*)(&Vs[vrow + t * 16][vc8]) = vv;
        }
        __syncthreads();

        // --- QK^T: 8 j-subtiles of 16 ---
        f32x4 s[8];
#pragma unroll
        for (int jt = 0; jt < 8; jt++) {
            bf16x8 kb0 = *(const bf16x8*)(&Ks[jt * 16 + l16][quad * 8]);
            bf16x8 kb1 = *(const bf16x8*)(&Ks[jt * 16 + l16][32 + quad * 8]);
            f32x4 a = {};
            a = MFMA16(qa0, kb0, a);
            a = MFMA16(qa1, kb1, a);
            s[jt] = a;
        }

        __syncthreads();  // all waves done reading Ks; Ps may overwrite it

        // --- P = exp2(s); mask only in the first iteration (diagonal) ---
        if (j0 == jstart) {
#pragma unroll
            for (int jt = 0; jt < 8; jt++) {
                int gj = j0 + jt * 16 + l16;
#pragma unroll
                for (int r = 0; r < 4; r++) {
                    int gi = iw + quad * 4 + r;
                    float p = (gj >= gi) ? __builtin_amdgcn_exp2f(s[jt][r]) : 0.0f;
                    Ps_w[(quad * 4 + r) * 136 + jt * 16 + l16] = (bf16_t)p;
                }
            }
        } else {
#pragma unroll
            for (int jt = 0; jt < 8; jt++)
#pragma unroll
                for (int r = 0; r < 4; r++)
                    Ps_w[(quad * 4 + r) * 136 + jt * 16 + l16] =
                        (bf16_t)__builtin_amdgcn_exp2f(s[jt][r]);
        }

        bf16x8 pa[4];
#pragma unroll
        for (int kk = 0; kk < 4; kk++) {
            pa[kk] = *(const bf16x8*)(&Ps_w[l16 * 136 + kk * 32 + quad * 8]);
            lacc = MFMA16(pa[kk], ones, lacc);
        }

        // --- PV from LDS V^T tile ---
#pragma unroll
        for (int nt = 0; nt < 4; nt++) {
#pragma unroll
            for (int kk = 0; kk < 4; kk++) {
                bf16x8 vb = *(const bf16x8*)(&Vs[nt * 16 + l16][kk * 32 + quad * 8]);
                o[nt] = MFMA16(pa[kk], vb, o[nt]);
            }
        }
    }

    // --- epilogue ---
#pragma unroll
    for (int r = 0; r < 4; r++) {
        int gi = iw + quad * 4 + r;
        float inv = 1.0f / lacc[r];
#pragma unroll
        for (int nt = 0; nt < 4; nt++)
            attn_out[(size_t)(b * SEQ + gi) * HID + h * HD + nt * 16 + l16] =
                (bf16_t)(o[nt][r] * inv);
    }
}

// ---------------------------------------------------------------------------
extern "C" void kernel_launch(void* const* d_in, const int* in_sizes, int n_in,
                              void* d_out, int out_size, void* d_ws, size_t ws_size,
                              hipStream_t stream) {
    const float* x     = (const float*)d_in[0];
    const float* w_qkv = (const float*)d_in[1];
    const float* b_qkv = (const float*)d_in[2];
    const float* w_out = (const float*)d_in[3];
    const float* b_out = (const float*)d_in[4];
    float* out = (float*)d_out;

    char* ws = (char*)d_ws;
    bf16_t* xbf   = (bf16_t*)(ws);               // 8.39 MB; dead after QKV GEMM
    bf16_t* Vt    = (bf16_t*)(ws);               // 8.52 MB; overruns into wqkvT
                                                 // (dead by vt_transpose time)
    bf16_t* wqkvT = (bf16_t*)(ws + 8388608);     // 6.29 MB
    bf16_t* woutT = (bf16_t*)(ws + 14680064);    // 2.10 MB (never overwritten)
    bf16_t* qkv   = (bf16_t*)(ws + 16777216);    // 25.17 MB
    bf16_t* attn  = (bf16_t*)(ws + 41943040);    // 8.39 MB

    prep_kernel<<<8192, 256, 0, stream>>>(x, w_qkv, w_out, xbf, wqkvT, woutT);

    gemm_bt_bias<bf16_t, 128><<<dim3(3072 / 128, 4096 / 128), 256, 0, stream>>>(
        xbf, wqkvT, b_qkv, qkv, 4096, 3072, 1024);

    vt_transpose<<<dim3(SEQ / 64, 2 * NHEAD), 256, 0, stream>>>(qkv, Vt);

    attn_kernel<<<dim3(32, 2 * NHEAD), 256, 0, stream>>>(qkv, Vt, attn);

    gemm_bt_bias<float, 64><<<dim3(1024 / 64, 4096 / 128), 256, 0, stream>>>(
        attn, woutT, b_out, out, 4096, 1024, 1024);
}

// Round 8
// 190.238 us; speedup vs baseline: 1.1368x; 1.1368x over previous
//
#include <hip/hip_runtime.h>
#include <hip/hip_bf16.h>
#include <stdint.h>
#include <stddef.h>

typedef __bf16 bf16_t;
typedef __bf16 bf16x4 __attribute__((ext_vector_type(4)));
typedef __bf16 bf16x8 __attribute__((ext_vector_type(8)));
typedef float f32x4 __attribute__((ext_vector_type(4)));

#define MFMA16(a, b, c) __builtin_amdgcn_mfma_f32_16x16x32_bf16(a, b, c, 0, 0, 0)

// async global->LDS, 16 B per lane; LDS dest = uniform base + lane*16
#define GLL16(g, l)                                                      \
    __builtin_amdgcn_global_load_lds(                                    \
        (const __attribute__((address_space(1))) void*)(g),              \
        (__attribute__((address_space(3))) void*)(l), 16, 0, 0)

#define SEQ 2048
#define NHEAD 16
#define HD 64
#define HID 1024
#define QKV_LD 3072
#define VT_LD 2080  // 2048 + 32 pad: breaks 4 KB power-of-2 L2 set aliasing

// ---------------------------------------------------------------------------
// Fused prep: cast x -> bf16 (blocks 0..4095), transpose+cast w_qkv
// (4096..7167), transpose+cast w_out (7168..8191).
// ---------------------------------------------------------------------------
__global__ __launch_bounds__(256)
void prep_kernel(const float* __restrict__ x, const float* __restrict__ w_qkv,
                 const float* __restrict__ w_out, bf16_t* __restrict__ xbf,
                 bf16_t* __restrict__ wqkvT, bf16_t* __restrict__ woutT) {
    int L = blockIdx.x;
    int tid = threadIdx.x;
    if (L < 4096) {  // cast x
        int i = (L * 256 + tid) * 4;
        float4 v = *(const float4*)(x + i);
        bf16x4 o = {(bf16_t)v.x, (bf16_t)v.y, (bf16_t)v.z, (bf16_t)v.w};
        *(bf16x4*)(xbf + i) = o;
        return;
    }
    __shared__ bf16_t tile[32][33];
    const float* W;
    bf16_t* Wt;
    int N, bx, by;
    if (L < 7168) {
        int r = L - 4096;
        W = w_qkv; Wt = wqkvT; N = 3072; bx = r % 96; by = r / 96;
    } else {
        int r = L - 7168;
        W = w_out; Wt = woutT; N = 1024; bx = r % 32; by = r / 32;
    }
    int K = 1024;
    int n0 = bx * 32, k0 = by * 32;
    int tx = tid & 31, ty = tid >> 5;  // 32 x 8
#pragma unroll
    for (int i = 0; i < 4; i++)
        tile[ty + i * 8][tx] = (bf16_t)W[(size_t)(k0 + ty + i * 8) * N + n0 + tx];
    __syncthreads();
#pragma unroll
    for (int i = 0; i < 4; i++)
        Wt[(size_t)(n0 + ty + i * 8) * K + k0 + tx] = tile[tx][ty + i * 8];
}

// ---------------------------------------------------------------------------
// V transpose prepass: Vt[bh][d][s] = qkv[b][s][2048 + h*64 + d].
// ---------------------------------------------------------------------------
__global__ __launch_bounds__(256)
void vt_transpose(const bf16_t* __restrict__ qkv, bf16_t* __restrict__ Vt) {
    int s0 = blockIdx.x * 64;
    int bh = blockIdx.y;
    int b = bh >> 4, h = bh & 15;
    int tid = threadIdx.x;
    __shared__ __align__(16) bf16_t tile[64][72];

    int row = tid >> 3, c8 = (tid & 7) * 8;
#pragma unroll
    for (int it = 0; it < 2; it++) {
        int sr = row + it * 32;
        bf16x8 v = *(const bf16x8*)(qkv + ((size_t)b * SEQ + s0 + sr) * QKV_LD +
                                    2 * HID + h * HD + c8);
        *(bf16x8*)(&tile[sr][c8]) = v;
    }
    __syncthreads();
#pragma unroll
    for (int it = 0; it < 2; it++) {
        int d = row + it * 32;
        bf16x8 w;
#pragma unroll
        for (int e = 0; e < 8; e++) w[e] = tile[c8 + e][d];
        *(bf16x8*)(Vt + ((size_t)bh * HD + d) * VT_LD + s0 + c8) = w;
    }
}

// ---------------------------------------------------------------------------
// GEMM: C[M][N] = A[M][K] @ Bt[N][K]^T + bias[N].  bf16, fp32 accum, OutT out.
// 128xTN tile, BK=32, 256 thr, GLL width-16 staging into unpadded LDS.
// ---------------------------------------------------------------------------
template <typename OutT, int TN>
__global__ __launch_bounds__(256)
void gemm_bt_bias(const bf16_t* __restrict__ A, const bf16_t* __restrict__ Bt,
                  const float* __restrict__ bias, OutT* __restrict__ C,
                  int M, int N, int K) {
    constexpr int NT = TN / 32;  // acc n-tiles per wave
    __shared__ __align__(16) bf16_t As[128][32];
    __shared__ __align__(16) bf16_t Bs[TN][32];

    int m0 = blockIdx.y * 128;
    int n0 = blockIdx.x * TN;
    int tid = threadIdx.x;
    int wave = tid >> 6, lane = tid & 63;
    int quad = lane >> 4, l16 = lane & 15;
    int wm = (wave >> 1) * 64, wn = (wave & 1) * (TN / 2);

    f32x4 acc[4][NT] = {};

    const bf16_t* a_base =
        A + (size_t)(m0 + wave * 32 + (lane >> 2)) * K + (lane & 3) * 8;
    const bf16_t* b_base =
        Bt + (size_t)(n0 + wave * (TN / 4) + (lane >> 2)) * K + (lane & 3) * 8;
    bf16_t* as_base = &As[wave * 32][0];
    bf16_t* bs_base = &Bs[wave * (TN / 4)][0];

    for (int k0 = 0; k0 < K; k0 += 32) {
        GLL16(a_base + k0, as_base);
        GLL16(a_base + 16 * K + k0, as_base + 16 * 32);
        GLL16(b_base + k0, bs_base);
        if (TN == 128) GLL16(b_base + 16 * K + k0, bs_base + 16 * 32);
        __syncthreads();

        bf16x8 af[4], bfr[NT];
#pragma unroll
        for (int t = 0; t < 4; t++)
            af[t] = *(const bf16x8*)(&As[wm + t * 16 + l16][quad * 8]);
#pragma unroll
        for (int t = 0; t < NT; t++)
            bfr[t] = *(const bf16x8*)(&Bs[wn + t * 16 + l16][quad * 8]);
#pragma unroll
        for (int mt = 0; mt < 4; mt++)
#pragma unroll
            for (int nt = 0; nt < NT; nt++)
                acc[mt][nt] = MFMA16(af[mt], bfr[nt], acc[mt][nt]);
        __syncthreads();
    }

#pragma unroll
    for (int mt = 0; mt < 4; mt++) {
        int row = m0 + wm + mt * 16 + quad * 4;
#pragma unroll
        for (int nt = 0; nt < NT; nt++) {
            int col = n0 + wn + nt * 16 + l16;
            float bv = bias[col];
#pragma unroll
            for (int r = 0; r < 4; r++)
                C[(size_t)(row + r) * N + col] = (OutT)(acc[mt][nt][r] + bv);
        }
    }
}

// ---------------------------------------------------------------------------
// Attention, mask j >= i.  Round-6 skeleton (paired i-tiles (t,31-t), BJ=128,
// wave-private Ps, 2 barriers/iter) + exp2/prescaled-Q/first-iter-only mask
// + REGISTER DOUBLE-BUFFER PREFETCH: next tile's K/V global loads issue right
// after the staging barrier and complete under this tile's compute.
// ---------------------------------------------------------------------------
__global__ __launch_bounds__(256)
void attn_kernel(const bf16_t* __restrict__ qkv, const bf16_t* __restrict__ Vt,
                 bf16_t* __restrict__ attn_out) {
    int L = blockIdx.y * 16 + blockIdx.x;
    int xcd = L & 7, idx = L >> 3;
    int bh = xcd + 8 * (idx >> 4);        // 4 bh groups per XCD (L2 locality)
    int xb = idx & 15;
    int b = bh >> 4, h = bh & 15;

    int tid = threadIdx.x, wave = tid >> 6, lane = tid & 63;
    int quad = lane >> 4, l16 = lane & 15;

    const bf16_t* q_g = qkv + (size_t)b * SEQ * QKV_LD + (size_t)h * HD;
    const bf16_t* k_g = q_g + HID;
    const bf16_t* vt_g = Vt + (size_t)bh * HD * VT_LD;

    __shared__ __align__(16) bf16_t Ks[128][72];     // K tile [j][d]
    __shared__ __align__(16) bf16_t Vs[64][136];     // V^T tile [d][j]
    __shared__ __align__(16) bf16_t Ps[4][16][136];  // wave-private P

    bf16x8 ones;
#pragma unroll
    for (int e = 0; e < 8; e++) ones[e] = (bf16_t)1.0f;

    int krow = tid >> 3, kc8 = (tid & 7) * 8;    // K staging: 32 rows/pass
    int vrow = tid >> 4, vc8 = (tid & 15) * 8;   // V staging: 16 rows/pass
    const float QS = 0.125f * 1.44269504088896f; // /sqrt(64) * log2(e)

#pragma unroll
    for (int phase = 0; phase < 2; phase++) {
        int tile = phase ? (31 - xb) : xb;
        int i0 = tile * 64;
        int iw = i0 + wave * 16;

        // Q fragments pre-scaled so P = exp2(s) directly.
        bf16x8 qa0, qa1;
        {
            bf16x8 t0 = *(const bf16x8*)(q_g + (size_t)(iw + l16) * QKV_LD + quad * 8);
            bf16x8 t1 = *(const bf16x8*)(q_g + (size_t)(iw + l16) * QKV_LD + 32 + quad * 8);
#pragma unroll
            for (int e = 0; e < 8; e++) {
                qa0[e] = (bf16_t)((float)t0[e] * QS);
                qa1[e] = (bf16_t)((float)t1[e] * QS);
            }
        }

        f32x4 o[4] = {};
        f32x4 lacc = {};

        int jstart = i0 & ~127;

        // --- preload first tile into registers ---
        bf16x8 kr[4], vr[4];
#pragma unroll
        for (int t = 0; t < 4; t++) {
            kr[t] = *(const bf16x8*)(k_g + (size_t)(jstart + krow + t * 32) * QKV_LD + kc8);
            vr[t] = *(const bf16x8*)(vt_g + (size_t)(vrow + t * 16) * VT_LD + jstart + vc8);
        }

        for (int j0 = jstart; j0 < SEQ; j0 += 128) {
            __syncthreads();  // prev iteration's LDS readers done
            // --- commit prefetched registers to LDS ---
#pragma unroll
            for (int t = 0; t < 4; t++) {
                *(bf16x8*)(&Ks[krow + t * 32][kc8]) = kr[t];
                *(bf16x8*)(&Vs[vrow + t * 16][vc8]) = vr[t];
            }
            __syncthreads();

            // --- issue next tile's loads; they land during compute below ---
            if (j0 + 128 < SEQ) {
#pragma unroll
                for (int t = 0; t < 4; t++) {
                    kr[t] = *(const bf16x8*)(k_g + (size_t)(j0 + 128 + krow + t * 32) * QKV_LD + kc8);
                    vr[t] = *(const bf16x8*)(vt_g + (size_t)(vrow + t * 16) * VT_LD + j0 + 128 + vc8);
                }
            }

            // --- QK^T: 8 j-subtiles of 16 ---
            f32x4 s[8];
#pragma unroll
            for (int jt = 0; jt < 8; jt++) {
                bf16x8 kb0 = *(const bf16x8*)(&Ks[jt * 16 + l16][quad * 8]);
                bf16x8 kb1 = *(const bf16x8*)(&Ks[jt * 16 + l16][32 + quad * 8]);
                f32x4 a = {};
                a = MFMA16(qa0, kb0, a);
                a = MFMA16(qa1, kb1, a);
                s[jt] = a;
            }

            // --- P = exp2(s); mask only in the first iteration (diagonal) ---
            if (j0 == jstart) {
#pragma unroll
                for (int jt = 0; jt < 8; jt++) {
                    int gj = j0 + jt * 16 + l16;
#pragma unroll
                    for (int r = 0; r < 4; r++) {
                        int gi = iw + quad * 4 + r;
                        float p = (gj >= gi) ? __builtin_amdgcn_exp2f(s[jt][r]) : 0.0f;
                        Ps[wave][quad * 4 + r][jt * 16 + l16] = (bf16_t)p;
                    }
                }
            } else {
#pragma unroll
                for (int jt = 0; jt < 8; jt++)
#pragma unroll
                    for (int r = 0; r < 4; r++)
                        Ps[wave][quad * 4 + r][jt * 16 + l16] =
                            (bf16_t)__builtin_amdgcn_exp2f(s[jt][r]);
            }

            bf16x8 pa[4];
#pragma unroll
            for (int kk = 0; kk < 4; kk++) {
                pa[kk] = *(const bf16x8*)(&Ps[wave][l16][kk * 32 + quad * 8]);
                lacc = MFMA16(pa[kk], ones, lacc);
            }

            // --- PV from LDS V^T tile ---
#pragma unroll
            for (int nt = 0; nt < 4; nt++) {
#pragma unroll
                for (int kk = 0; kk < 4; kk++) {
                    bf16x8 vb = *(const bf16x8*)(&Vs[nt * 16 + l16][kk * 32 + quad * 8]);
                    o[nt] = MFMA16(pa[kk], vb, o[nt]);
                }
            }
        }

        // --- epilogue ---
#pragma unroll
        for (int r = 0; r < 4; r++) {
            int gi = iw + quad * 4 + r;
            float inv = 1.0f / lacc[r];
#pragma unroll
            for (int nt = 0; nt < 4; nt++)
                attn_out[(size_t)(b * SEQ + gi) * HID + h * HD + nt * 16 + l16] =
                    (bf16_t)(o[nt][r] * inv);
        }
    }
}

// ---------------------------------------------------------------------------
extern "C" void kernel_launch(void* const* d_in, const int* in_sizes, int n_in,
                              void* d_out, int out_size, void* d_ws, size_t ws_size,
                              hipStream_t stream) {
    const float* x     = (const float*)d_in[0];
    const float* w_qkv = (const float*)d_in[1];
    const float* b_qkv = (const float*)d_in[2];
    const float* w_out = (const float*)d_in[3];
    const float* b_out = (const float*)d_in[4];
    float* out = (float*)d_out;

    char* ws = (char*)d_ws;
    bf16_t* xbf   = (bf16_t*)(ws);               // 8.39 MB; dead after QKV GEMM
    bf16_t* Vt    = (bf16_t*)(ws);               // 8.52 MB; overruns into wqkvT
                                                 // (dead by vt_transpose time)
    bf16_t* wqkvT = (bf16_t*)(ws + 8388608);     // 6.29 MB
    bf16_t* woutT = (bf16_t*)(ws + 14680064);    // 2.10 MB (never overwritten)
    bf16_t* qkv   = (bf16_t*)(ws + 16777216);    // 25.17 MB
    bf16_t* attn  = (bf16_t*)(ws + 41943040);    // 8.39 MB

    prep_kernel<<<8192, 256, 0, stream>>>(x, w_qkv, w_out, xbf, wqkvT, woutT);

    gemm_bt_bias<bf16_t, 128><<<dim3(3072 / 128, 4096 / 128), 256, 0, stream>>>(
        xbf, wqkvT, b_qkv, qkv, 4096, 3072, 1024);

    vt_transpose<<<dim3(SEQ / 64, 2 * NHEAD), 256, 0, stream>>>(qkv, Vt);

    attn_kernel<<<dim3(16, 2 * NHEAD), 256, 0, stream>>>(qkv, Vt, attn);

    gemm_bt_bias<float, 64><<<dim3(1024 / 64, 4096 / 128), 256, 0, stream>>>(
        attn, woutT, b_out, out, 4096, 1024, 1024);
}

// Round 9
// 187.914 us; speedup vs baseline: 1.1509x; 1.0124x over previous
//
#include <hip/hip_runtime.h>
#include <hip/hip_bf16.h>
#include <stdint.h>
#include <stddef.h>

typedef __bf16 bf16_t;
typedef __bf16 bf16x4 __attribute__((ext_vector_type(4)));
typedef __bf16 bf16x8 __attribute__((ext_vector_type(8)));
typedef float f32x4 __attribute__((ext_vector_type(4)));

#define MFMA16(a, b, c) __builtin_amdgcn_mfma_f32_16x16x32_bf16(a, b, c, 0, 0, 0)

// async global->LDS, 16 B per lane; LDS dest = uniform base + lane*16
#define GLL16(g, l)                                                      \
    __builtin_amdgcn_global_load_lds(                                    \
        (const __attribute__((address_space(1))) void*)(g),              \
        (__attribute__((address_space(3))) void*)(l), 16, 0, 0)

#define SEQ 2048
#define NHEAD 16
#define HD 64
#define HID 1024
#define QKV_LD 3072
#define VT_LD 2080  // 2048 + 32 pad: breaks 4 KB power-of-2 L2 set aliasing

// ---------------------------------------------------------------------------
// Fused prep: cast x -> bf16 (blocks 0..4095), transpose+cast w_qkv
// (4096..7167), transpose+cast w_out (7168..8191).
// ---------------------------------------------------------------------------
__global__ __launch_bounds__(256)
void prep_kernel(const float* __restrict__ x, const float* __restrict__ w_qkv,
                 const float* __restrict__ w_out, bf16_t* __restrict__ xbf,
                 bf16_t* __restrict__ wqkvT, bf16_t* __restrict__ woutT) {
    int L = blockIdx.x;
    int tid = threadIdx.x;
    if (L < 4096) {  // cast x
        int i = (L * 256 + tid) * 4;
        float4 v = *(const float4*)(x + i);
        bf16x4 o = {(bf16_t)v.x, (bf16_t)v.y, (bf16_t)v.z, (bf16_t)v.w};
        *(bf16x4*)(xbf + i) = o;
        return;
    }
    __shared__ bf16_t tile[32][33];
    const float* W;
    bf16_t* Wt;
    int N, bx, by;
    if (L < 7168) {
        int r = L - 4096;
        W = w_qkv; Wt = wqkvT; N = 3072; bx = r % 96; by = r / 96;
    } else {
        int r = L - 7168;
        W = w_out; Wt = woutT; N = 1024; bx = r % 32; by = r / 32;
    }
    int K = 1024;
    int n0 = bx * 32, k0 = by * 32;
    int tx = tid & 31, ty = tid >> 5;  // 32 x 8
#pragma unroll
    for (int i = 0; i < 4; i++)
        tile[ty + i * 8][tx] = (bf16_t)W[(size_t)(k0 + ty + i * 8) * N + n0 + tx];
    __syncthreads();
#pragma unroll
    for (int i = 0; i < 4; i++)
        Wt[(size_t)(n0 + ty + i * 8) * K + k0 + tx] = tile[tx][ty + i * 8];
}

// ---------------------------------------------------------------------------
// V transpose prepass: Vt[bh][d][s] = qkv[b][s][2048 + h*64 + d].
// ---------------------------------------------------------------------------
__global__ __launch_bounds__(256)
void vt_transpose(const bf16_t* __restrict__ qkv, bf16_t* __restrict__ Vt) {
    int s0 = blockIdx.x * 64;
    int bh = blockIdx.y;
    int b = bh >> 4, h = bh & 15;
    int tid = threadIdx.x;
    __shared__ __align__(16) bf16_t tile[64][72];

    int row = tid >> 3, c8 = (tid & 7) * 8;
#pragma unroll
    for (int it = 0; it < 2; it++) {
        int sr = row + it * 32;
        bf16x8 v = *(const bf16x8*)(qkv + ((size_t)b * SEQ + s0 + sr) * QKV_LD +
                                    2 * HID + h * HD + c8);
        *(bf16x8*)(&tile[sr][c8]) = v;
    }
    __syncthreads();
#pragma unroll
    for (int it = 0; it < 2; it++) {
        int d = row + it * 32;
        bf16x8 w;
#pragma unroll
        for (int e = 0; e < 8; e++) w[e] = tile[c8 + e][d];
        *(bf16x8*)(Vt + ((size_t)bh * HD + d) * VT_LD + s0 + c8) = w;
    }
}

// ---------------------------------------------------------------------------
// GEMM: C[M][N] = A[M][K] @ Bt[N][K]^T + bias[N].  bf16, fp32 accum, OutT out.
// 128xTN tile, BK=32, 256 thr, GLL width-16 staging into unpadded LDS.
// ---------------------------------------------------------------------------
template <typename OutT, int TN>
__global__ __launch_bounds__(256)
void gemm_bt_bias(const bf16_t* __restrict__ A, const bf16_t* __restrict__ Bt,
                  const float* __restrict__ bias, OutT* __restrict__ C,
                  int M, int N, int K) {
    constexpr int NT = TN / 32;  // acc n-tiles per wave
    __shared__ __align__(16) bf16_t As[128][32];
    __shared__ __align__(16) bf16_t Bs[TN][32];

    int m0 = blockIdx.y * 128;
    int n0 = blockIdx.x * TN;
    int tid = threadIdx.x;
    int wave = tid >> 6, lane = tid & 63;
    int quad = lane >> 4, l16 = lane & 15;
    int wm = (wave >> 1) * 64, wn = (wave & 1) * (TN / 2);

    f32x4 acc[4][NT] = {};

    const bf16_t* a_base =
        A + (size_t)(m0 + wave * 32 + (lane >> 2)) * K + (lane & 3) * 8;
    const bf16_t* b_base =
        Bt + (size_t)(n0 + wave * (TN / 4) + (lane >> 2)) * K + (lane & 3) * 8;
    bf16_t* as_base = &As[wave * 32][0];
    bf16_t* bs_base = &Bs[wave * (TN / 4)][0];

    for (int k0 = 0; k0 < K; k0 += 32) {
        GLL16(a_base + k0, as_base);
        GLL16(a_base + 16 * K + k0, as_base + 16 * 32);
        GLL16(b_base + k0, bs_base);
        if (TN == 128) GLL16(b_base + 16 * K + k0, bs_base + 16 * 32);
        __syncthreads();

        bf16x8 af[4], bfr[NT];
#pragma unroll
        for (int t = 0; t < 4; t++)
            af[t] = *(const bf16x8*)(&As[wm + t * 16 + l16][quad * 8]);
#pragma unroll
        for (int t = 0; t < NT; t++)
            bfr[t] = *(const bf16x8*)(&Bs[wn + t * 16 + l16][quad * 8]);
#pragma unroll
        for (int mt = 0; mt < 4; mt++)
#pragma unroll
            for (int nt = 0; nt < NT; nt++)
                acc[mt][nt] = MFMA16(af[mt], bfr[nt], acc[mt][nt]);
        __syncthreads();
    }

#pragma unroll
    for (int mt = 0; mt < 4; mt++) {
        int row = m0 + wm + mt * 16 + quad * 4;
#pragma unroll
        for (int nt = 0; nt < NT; nt++) {
            int col = n0 + wn + nt * 16 + l16;
            float bv = bias[col];
#pragma unroll
            for (int r = 0; r < 4; r++)
                C[(size_t)(row + r) * N + col] = (OutT)(acc[mt][nt][r] + bv);
        }
    }
}

// ---------------------------------------------------------------------------
// Attention, mask j >= i.  Round-8 inner loop (BJ=128, wave-private Ps,
// 2 barriers/iter, register double-buffer prefetch, exp2 + prescaled Q,
// first-iter-only mask).  UNPAIRED grid (32 bh x 32 tiles): LDS 52 KB fits
// 3 blocks/CU -> 3 waves/SIMD (was 2), and y=tile dispatch order runs long
// blocks (tile 0: 16 iters) first, short (1 iter) last -> LPT balance.
// XCD pinning preserved: linear%8 = bh%8.
// ---------------------------------------------------------------------------
__global__ __launch_bounds__(256)
void attn_kernel(const bf16_t* __restrict__ qkv, const bf16_t* __restrict__ Vt,
                 bf16_t* __restrict__ attn_out) {
    int bh = blockIdx.x;        // x fastest -> XCD = bh%8 (L2 locality)
    int tile = blockIdx.y;      // y-major dispatch -> tile 0 (longest) first
    int b = bh >> 4, h = bh & 15;

    int tid = threadIdx.x, wave = tid >> 6, lane = tid & 63;
    int quad = lane >> 4, l16 = lane & 15;

    const bf16_t* q_g = qkv + (size_t)b * SEQ * QKV_LD + (size_t)h * HD;
    const bf16_t* k_g = q_g + HID;
    const bf16_t* vt_g = Vt + (size_t)bh * HD * VT_LD;

    __shared__ __align__(16) bf16_t Ks[128][72];     // K tile [j][d]
    __shared__ __align__(16) bf16_t Vs[64][136];     // V^T tile [d][j]
    __shared__ __align__(16) bf16_t Ps[4][16][136];  // wave-private P

    bf16x8 ones;
#pragma unroll
    for (int e = 0; e < 8; e++) ones[e] = (bf16_t)1.0f;

    int krow = tid >> 3, kc8 = (tid & 7) * 8;    // K staging: 32 rows/pass
    int vrow = tid >> 4, vc8 = (tid & 15) * 8;   // V staging: 16 rows/pass
    const float QS = 0.125f * 1.44269504088896f; // /sqrt(64) * log2(e)

    int i0 = tile * 64;
    int iw = i0 + wave * 16;

    // Q fragments pre-scaled so P = exp2(s) directly.
    bf16x8 qa0, qa1;
    {
        bf16x8 t0 = *(const bf16x8*)(q_g + (size_t)(iw + l16) * QKV_LD + quad * 8);
        bf16x8 t1 = *(const bf16x8*)(q_g + (size_t)(iw + l16) * QKV_LD + 32 + quad * 8);
#pragma unroll
        for (int e = 0; e < 8; e++) {
            qa0[e] = (bf16_t)((float)t0[e] * QS);
            qa1[e] = (bf16_t)((float)t1[e] * QS);
        }
    }

    f32x4 o[4] = {};
    f32x4 lacc = {};

    int jstart = i0 & ~127;

    // --- preload first tile into registers ---
    bf16x8 kr[4], vr[4];
#pragma unroll
    for (int t = 0; t < 4; t++) {
        kr[t] = *(const bf16x8*)(k_g + (size_t)(jstart + krow + t * 32) * QKV_LD + kc8);
        vr[t] = *(const bf16x8*)(vt_g + (size_t)(vrow + t * 16) * VT_LD + jstart + vc8);
    }

    for (int j0 = jstart; j0 < SEQ; j0 += 128) {
        __syncthreads();  // prev iteration's LDS readers done
        // --- commit prefetched registers to LDS ---
#pragma unroll
        for (int t = 0; t < 4; t++) {
            *(bf16x8*)(&Ks[krow + t * 32][kc8]) = kr[t];
            *(bf16x8*)(&Vs[vrow + t * 16][vc8]) = vr[t];
        }
        __syncthreads();

        // --- issue next tile's loads; they land during compute below ---
        if (j0 + 128 < SEQ) {
#pragma unroll
            for (int t = 0; t < 4; t++) {
                kr[t] = *(const bf16x8*)(k_g + (size_t)(j0 + 128 + krow + t * 32) * QKV_LD + kc8);
                vr[t] = *(const bf16x8*)(vt_g + (size_t)(vrow + t * 16) * VT_LD + j0 + 128 + vc8);
            }
        }

        // --- QK^T: 8 j-subtiles of 16 ---
        f32x4 s[8];
#pragma unroll
        for (int jt = 0; jt < 8; jt++) {
            bf16x8 kb0 = *(const bf16x8*)(&Ks[jt * 16 + l16][quad * 8]);
            bf16x8 kb1 = *(const bf16x8*)(&Ks[jt * 16 + l16][32 + quad * 8]);
            f32x4 a = {};
            a = MFMA16(qa0, kb0, a);
            a = MFMA16(qa1, kb1, a);
            s[jt] = a;
        }

        // --- P = exp2(s); mask only in the first iteration (diagonal) ---
        if (j0 == jstart) {
#pragma unroll
            for (int jt = 0; jt < 8; jt++) {
                int gj = j0 + jt * 16 + l16;
#pragma unroll
                for (int r = 0; r < 4; r++) {
                    int gi = iw + quad * 4 + r;
                    float p = (gj >= gi) ? __builtin_amdgcn_exp2f(s[jt][r]) : 0.0f;
                    Ps[wave][quad * 4 + r][jt * 16 + l16] = (bf16_t)p;
                }
            }
        } else {
#pragma unroll
            for (int jt = 0; jt < 8; jt++)
#pragma unroll
                for (int r = 0; r < 4; r++)
                    Ps[wave][quad * 4 + r][jt * 16 + l16] =
                        (bf16_t)__builtin_amdgcn_exp2f(s[jt][r]);
        }

        bf16x8 pa[4];
#pragma unroll
        for (int kk = 0; kk < 4; kk++) {
            pa[kk] = *(const bf16x8*)(&Ps[wave][l16][kk * 32 + quad * 8]);
            lacc = MFMA16(pa[kk], ones, lacc);
        }

        // --- PV from LDS V^T tile ---
#pragma unroll
        for (int nt = 0; nt < 4; nt++) {
#pragma unroll
            for (int kk = 0; kk < 4; kk++) {
                bf16x8 vb = *(const bf16x8*)(&Vs[nt * 16 + l16][kk * 32 + quad * 8]);
                o[nt] = MFMA16(pa[kk], vb, o[nt]);
            }
        }
    }

    // --- epilogue ---
#pragma unroll
    for (int r = 0; r < 4; r++) {
        int gi = iw + quad * 4 + r;
        float inv = 1.0f / lacc[r];
#pragma unroll
        for (int nt = 0; nt < 4; nt++)
            attn_out[(size_t)(b * SEQ + gi) * HID + h * HD + nt * 16 + l16] =
                (bf16_t)(o[nt][r] * inv);
    }
}

// ---------------------------------------------------------------------------
extern "C" void kernel_launch(void* const* d_in, const int* in_sizes, int n_in,
                              void* d_out, int out_size, void* d_ws, size_t ws_size,
                              hipStream_t stream) {
    const float* x     = (const float*)d_in[0];
    const float* w_qkv = (const float*)d_in[1];
    const float* b_qkv = (const float*)d_in[2];
    const float* w_out = (const float*)d_in[3];
    const float* b_out = (const float*)d_in[4];
    float* out = (float*)d_out;

    char* ws = (char*)d_ws;
    bf16_t* xbf   = (bf16_t*)(ws);               // 8.39 MB; dead after QKV GEMM
    bf16_t* Vt    = (bf16_t*)(ws);               // 8.52 MB; overruns into wqkvT
                                                 // (dead by vt_transpose time)
    bf16_t* wqkvT = (bf16_t*)(ws + 8388608);     // 6.29 MB
    bf16_t* woutT = (bf16_t*)(ws + 14680064);    // 2.10 MB (never overwritten)
    bf16_t* qkv   = (bf16_t*)(ws + 16777216);    // 25.17 MB
    bf16_t* attn  = (bf16_t*)(ws + 41943040);    // 8.39 MB

    prep_kernel<<<8192, 256, 0, stream>>>(x, w_qkv, w_out, xbf, wqkvT, woutT);

    gemm_bt_bias<bf16_t, 128><<<dim3(3072 / 128, 4096 / 128), 256, 0, stream>>>(
        xbf, wqkvT, b_qkv, qkv, 4096, 3072, 1024);

    vt_transpose<<<dim3(SEQ / 64, 2 * NHEAD), 256, 0, stream>>>(qkv, Vt);

    attn_kernel<<<dim3(2 * NHEAD, SEQ / 64), 256, 0, stream>>>(qkv, Vt, attn);

    gemm_bt_bias<float, 64><<<dim3(1024 / 64, 4096 / 128), 256, 0, stream>>>(
        attn, woutT, b_out, out, 4096, 1024, 1024);
}